// Round 8
// baseline (285.023 us; speedup 1.0000x reference)
//
#include <hip/hip_runtime.h>
#include <hip/hip_bf16.h>
#include <stdint.h>

#define H 128
#define NNODES 100000
#define NEDGE 500000
#define MT 32                  // node rows per GEMM tile (100000 = 3125*32 exact)
#define NT2 6250               // tiles across both z inputs (z-interleaved)
#define GEMM_GRID 1024         // 4 blocks/CU (LDS 33 KB)
#define EPI_S 266              // ebuf stride in ushorts (256 + 10 pad)

// ws layout:
//   [0, 65536)        : Bsw  bf16, fragment-swizzled w1 (16 kb-groups x 256 cols x 8)
//   [65536, +25.6MB)x4: T_ps, T_pd, T_os, T_od  bf16 [100000][128]
#define BSW_BYTES 65536
#define TBL_ELEMS (NNODES * H)
#define WS_NEEDED ((size_t)BSW_BYTES + 4ULL * TBL_ELEMS * 2ULL)

typedef __bf16 bf16x8 __attribute__((ext_vector_type(8)));
typedef float f32x4 __attribute__((ext_vector_type(4)));

union frag_cast { uint4 u; bf16x8 b; ushort s[8]; };

__device__ __forceinline__ ushort f2bf(float f) {
    __hip_bfloat16 h = __float2bfloat16(f);
    return *(ushort*)&h;
}

__device__ __forceinline__ void bf2_to_f(uint32_t u, float& lo, float& hi) {
    union { uint32_t i; float f; } a, b;
    a.i = u << 16;
    b.i = u & 0xffff0000u;
    lo = a.f;
    hi = b.f;
}

// Build fragment-swizzled bf16 B from w1.
__global__ __launch_bounds__(256) void prep_bsw(const float* __restrict__ w1,
                                                ushort* __restrict__ bsw) {
    int i = blockIdx.x * 256 + threadIdx.x;  // 0..32767
    int j = i & 7;
    int n = (i >> 3) & 255;
    int kb = i >> 11;
    int k = kb * 8 + j;
    int r = (n < 128) ? k : (128 + k);
    int c = n & 127;
    bsw[i] = f2bf(w1[r * H + c]);
}

// Persistent GEMM, 256 thr = 4 waves, tile = [32 rows x 256 cols].
// Single 16 KB A buffer staged via global_load_lds dwordx4 (XOR source
// swizzle) + 17 KB coalesced epilogue buffer = 33 KB -> 4 blocks/CU.
// R6 lesson: dbuf prefetch was neutral at 3 blocks/CU; the limiter (per
// r5's counters) is memory parallelism, so trade the prefetch buffer for
// +33% occupancy and let cross-block overlap hide the per-tile DMA drain.
__global__ __launch_bounds__(256, 4) void gemm_tables(
    const float* __restrict__ zp, const float* __restrict__ zo,
    const ushort* __restrict__ bsw, const float* __restrict__ b1,
    ushort* __restrict__ t_ps, ushort* __restrict__ t_pd,
    ushort* __restrict__ t_os, ushort* __restrict__ t_od) {
    __shared__ float abuf[MT * H];       // 16 KB A staging
    __shared__ ushort ebuf[MT * EPI_S];  // 17 KB epilogue staging

    const int t = threadIdx.x;
    const int wave = t >> 6;
    const int lane = t & 63;
    const int l15 = lane & 15;
    const int quad = lane >> 4;
    const int n0 = wave * 64;            // wave's output col base (0..255)
    const int half = wave >> 1;          // 0: s-cols, 1: d-cols

    // ---- Per-block constants: B fragments (16 x 16B, L2-hot) + bias ----
    frag_cast bfr[4][4];
#pragma unroll
    for (int s = 0; s < 4; ++s)
#pragma unroll
        for (int nt = 0; nt < 4; ++nt)
            bfr[s][nt].u = *(const uint4*)(bsw + ((s * 4 + quad) * 256 + n0 + nt * 16 + l15) * 8);

    float bias[4] = {0.f, 0.f, 0.f, 0.f};
    if (half) {
#pragma unroll
        for (int nt = 0; nt < 4; ++nt)
            bias[nt] = b1[(n0 - 128) + nt * 16 + l15];
    }

    // Staging offsets (constant across tiles):
    int src_off[4], lds_off[4];
#pragma unroll
    for (int i = 0; i < 4; ++i) {
        const int r = (wave * 4 + i) * 2 + (lane >> 5);
        const int jsrc = (lane & 31) ^ (r & 15);
        src_off[i] = r * H + jsrc * 4;      // floats
        lds_off[i] = (wave * 4 + i) * 256;  // floats
    }

    for (int tile = blockIdx.x; tile < NT2; tile += GEMM_GRID) {
        const int zsel = tile & 1;
        const int node0 = (tile >> 1) * MT;
        const float* zt = (zsel ? zo : zp) + (size_t)node0 * H;

        // ---- Stage A: 16 global_load_lds_dwordx4 across block (16 KB) ----
#pragma unroll
        for (int i = 0; i < 4; ++i)
            __builtin_amdgcn_global_load_lds(
                (const __attribute__((address_space(1))) uint32_t*)(zt + src_off[i]),
                (__attribute__((address_space(3))) uint32_t*)(abuf + lds_off[i]),
                16, 0, 0);
        __syncthreads();  // drain DMA; also fences ebuf reuse from prev tile

        // ---- Compute: rows 0..31 (2 mt), wave cols n0..n0+63 (4 nt), K=128 ----
        f32x4 acc[2][4];
#pragma unroll
        for (int mt = 0; mt < 2; ++mt)
#pragma unroll
            for (int nt = 0; nt < 4; ++nt)
                acc[mt][nt] = (f32x4){0.f, 0.f, 0.f, 0.f};

#pragma unroll
        for (int s = 0; s < 4; ++s)
#pragma unroll
            for (int mt = 0; mt < 2; ++mt) {
                const int row = mt * 16 + l15;
                const int c = s * 4 + quad;  // 32B chunk -> b128 units 2c, 2c+1
                const float4 vlo = *(const float4*)(abuf + row * H + ((2 * c) ^ l15) * 4);
                const float4 vhi = *(const float4*)(abuf + row * H + ((2 * c + 1) ^ l15) * 4);
                frag_cast a;
                a.s[0] = f2bf(vlo.x); a.s[1] = f2bf(vlo.y);
                a.s[2] = f2bf(vlo.z); a.s[3] = f2bf(vlo.w);
                a.s[4] = f2bf(vhi.x); a.s[5] = f2bf(vhi.y);
                a.s[6] = f2bf(vhi.z); a.s[7] = f2bf(vhi.w);
#pragma unroll
                for (int nt = 0; nt < 4; ++nt)
                    acc[mt][nt] = __builtin_amdgcn_mfma_f32_16x16x32_bf16(
                        a.b, bfr[s][nt].b, acc[mt][nt], 0, 0, 0);
            }

        // ---- Epilogue stage: acc -> ebuf (D: col=l15, row=quad*4+reg) ----
#pragma unroll
        for (int mt = 0; mt < 2; ++mt)
#pragma unroll
            for (int nt = 0; nt < 4; ++nt) {
                const int col = n0 + nt * 16 + l15;
#pragma unroll
                for (int r = 0; r < 4; ++r)
                    ebuf[(mt * 16 + quad * 4 + r) * EPI_S + col] =
                        f2bf(acc[mt][nt][r] + bias[nt]);
            }

        __syncthreads();  // ebuf ready; abuf free for next tile

        // ---- Coalesced stores: 1024 chunks of 16B; wave writes 4 KB contig ----
        ushort* __restrict__ stab = zsel ? t_os : t_ps;
        ushort* __restrict__ dtab = zsel ? t_od : t_pd;
#pragma unroll
        for (int i = 0; i < 4; ++i) {
            const int c = i * 256 + t;        // 0..1023
            const int table = c >> 9;         // 0: s-table, 1: d-table
            const int row = (c >> 4) & 31;
            const int ch = c & 15;            // 16B chunk within row
            ushort* __restrict__ dst = table ? dtab : stab;
            *(uint4*)(dst + (size_t)(node0 + row) * H + ch * 8) =
                *(const uint4*)(ebuf + row * EPI_S + table * 128 + ch * 8);
        }
    }
}

// 16 lanes per group; each group handles 8 consecutive edges (16 outstanding
// 256-B gathers per lane-group). Each lane covers 8 channels (16B bf16 loads).
__global__ __launch_bounds__(256) void edge_kernel(
    const __hip_bfloat16* __restrict__ t_ps, const __hip_bfloat16* __restrict__ t_pd,
    const __hip_bfloat16* __restrict__ t_os, const __hip_bfloat16* __restrict__ t_od,
    const int* __restrict__ ptnp, const int* __restrict__ nptp,
    const int* __restrict__ nptnp,
    const float* __restrict__ w2, const float* __restrict__ b2,
    float* __restrict__ out) {
    const int tid = blockIdx.x * 256 + threadIdx.x;
    const int gg = tid >> 4;       // group id, 0..187499
    if (gg >= (3 * NEDGE) / 8) return;
    const int lane = tid & 15;
    const int e0 = gg * 8;         // 8 edges; 500000%8==0 so no type straddle

    const __hip_bfloat16 *src_tbl, *dst_tbl;
    const int* idx;
    int ebase;
    if (e0 < NEDGE) {
        idx = ptnp; ebase = e0;
        src_tbl = t_ps; dst_tbl = t_od;
    } else if (e0 < 2 * NEDGE) {
        idx = nptp; ebase = e0 - NEDGE;
        src_tbl = t_os; dst_tbl = t_pd;
    } else {
        idx = nptnp; ebase = e0 - 2 * NEDGE;
        src_tbl = t_os; dst_tbl = t_od;
    }

    const int4 sia = *(const int4*)(idx + ebase);
    const int4 sib = *(const int4*)(idx + ebase + 4);
    const int4 dia = *(const int4*)(idx + NEDGE + ebase);
    const int4 dib = *(const int4*)(idx + NEDGE + ebase + 4);

    int se[8], de[8];
    se[0] = sia.x; se[1] = sia.y; se[2] = sia.z; se[3] = sia.w;
    se[4] = sib.x; se[5] = sib.y; se[6] = sib.z; se[7] = sib.w;
    de[0] = dia.x; de[1] = dia.y; de[2] = dia.z; de[3] = dia.w;
    de[4] = dib.x; de[5] = dib.y; de[6] = dib.z; de[7] = dib.w;

    // 16 independent 16B gathers per lane, all issued before first use.
    uint4 sv[8], dv[8];
#pragma unroll
    for (int e = 0; e < 8; ++e) {
        sv[e] = *(const uint4*)(src_tbl + (size_t)se[e] * H + lane * 8);
        dv[e] = *(const uint4*)(dst_tbl + (size_t)de[e] * H + lane * 8);
    }

    const float4 w2a = *(const float4*)(w2 + lane * 8);
    const float4 w2b = *(const float4*)(w2 + lane * 8 + 4);
    const float wv[8] = {w2a.x, w2a.y, w2a.z, w2a.w, w2b.x, w2b.y, w2b.z, w2b.w};

    float sum[8];
#pragma unroll
    for (int e = 0; e < 8; ++e) {
        const uint32_t* su = (const uint32_t*)&sv[e];
        const uint32_t* du = (const uint32_t*)&dv[e];
        float acc = 0.f;
#pragma unroll
        for (int q = 0; q < 4; ++q) {
            float a0, a1, b0, b1v;
            bf2_to_f(su[q], a0, a1);
            bf2_to_f(du[q], b0, b1v);
            acc = fmaf(fmaxf(a0 + b0, 0.f), wv[2 * q], acc);
            acc = fmaf(fmaxf(a1 + b1v, 0.f), wv[2 * q + 1], acc);
        }
        sum[e] = acc;
    }

#pragma unroll
    for (int e = 0; e < 8; ++e) {
        sum[e] += __shfl_down(sum[e], 8, 16);
        sum[e] += __shfl_down(sum[e], 4, 16);
        sum[e] += __shfl_down(sum[e], 2, 16);
        sum[e] += __shfl_down(sum[e], 1, 16);
    }
    if (lane == 0) {
        const float bb = b2[0];
        float4 o0 = {sum[0] + bb, sum[1] + bb, sum[2] + bb, sum[3] + bb};
        float4 o1 = {sum[4] + bb, sum[5] + bb, sum[6] + bb, sum[7] + bb};
        *(float4*)(out + e0) = o0;
        *(float4*)(out + e0 + 4) = o1;
    }
}

// Fallback (only if ws_size is too small): direct per-edge compute, fp32.
__global__ __launch_bounds__(128) void edge_direct(
    const float* __restrict__ zp, const float* __restrict__ zo,
    const int* __restrict__ ptnp, const int* __restrict__ nptp,
    const int* __restrict__ nptnp,
    const float* __restrict__ w1, const float* __restrict__ b1,
    const float* __restrict__ w2, const float* __restrict__ b2,
    float* __restrict__ out) {
    const int g = blockIdx.x;
    const int j = threadIdx.x;

    const float *src, *dst;
    int si, di;
    if (g < NEDGE) {
        si = ptnp[g]; di = ptnp[NEDGE + g]; src = zp; dst = zo;
    } else if (g < 2 * NEDGE) {
        const int e = g - NEDGE;
        si = nptp[e]; di = nptp[NEDGE + e]; src = zo; dst = zp;
    } else {
        const int e = g - 2 * NEDGE;
        si = nptnp[e]; di = nptnp[NEDGE + e]; src = zo; dst = zo;
    }
    const float* zs = src + si * H;
    const float* zd = dst + di * H;

    float acc = b1[j];
    for (int k = 0; k < H; ++k) acc = fmaf(zs[k], w1[k * H + j], acc);
    for (int k = 0; k < H; ++k) acc = fmaf(zd[k], w1[(H + k) * H + j], acc);
    float v = fmaxf(acc, 0.f) * w2[j];

    for (int off = 32; off > 0; off >>= 1) v += __shfl_down(v, off, 64);
    __shared__ float parts[2];
    if ((j & 63) == 0) parts[j >> 6] = v;
    __syncthreads();
    if (j == 0) out[g] = parts[0] + parts[1] + b2[0];
}

extern "C" void kernel_launch(void* const* d_in, const int* in_sizes, int n_in,
                              void* d_out, int out_size, void* d_ws, size_t ws_size,
                              hipStream_t stream) {
    const float* zp    = (const float*)d_in[0];
    const float* zo    = (const float*)d_in[1];
    const int*   ptnp  = (const int*)d_in[2];
    const int*   nptp  = (const int*)d_in[3];
    const int*   nptnp = (const int*)d_in[4];
    const float* w1    = (const float*)d_in[5];
    const float* b1    = (const float*)d_in[6];
    const float* w2    = (const float*)d_in[7];
    const float* b2    = (const float*)d_in[8];
    float* out = (float*)d_out;

    if (ws_size < WS_NEEDED) {
        edge_direct<<<3 * NEDGE, 128, 0, stream>>>(zp, zo, ptnp, nptp, nptnp,
                                                   w1, b1, w2, b2, out);
        return;
    }

    char* ws = (char*)d_ws;
    ushort* bsw = (ushort*)ws;
    ushort* t_ps = (ushort*)(ws + BSW_BYTES);
    ushort* t_pd = t_ps + TBL_ELEMS;
    ushort* t_os = t_pd + TBL_ELEMS;
    ushort* t_od = t_os + TBL_ELEMS;

    prep_bsw<<<128, 256, 0, stream>>>(w1, bsw);

    gemm_tables<<<GEMM_GRID, 256, 0, stream>>>(
        zp, zo, bsw, b1, t_ps, t_pd, t_os, t_od);

    const int ngroups = (3 * NEDGE) / 8;                 // 187500
    const int nblocks = (ngroups * 16 + 255) / 256;      // 11719
    edge_kernel<<<nblocks, 256, 0, stream>>>(
        (const __hip_bfloat16*)t_ps, (const __hip_bfloat16*)t_pd,
        (const __hip_bfloat16*)t_os, (const __hip_bfloat16*)t_od,
        ptnp, nptp, nptnp, w2, b2, out);
}